// Round 2
// baseline (392.143 us; speedup 1.0000x reference)
//
#include <hip/hip_runtime.h>

// Causal Toeplitz-conv GEMM: y[b,h,n] = sum_{m<=n} u[b,h,m]*K[h,n-m] + D[h]*u[b,h,n]
// Output complex64 interleaved (re, 0) if out_size >= 2*B*H*L floats, else real plane.
// Workgroup: (h, group of IGRP=16 output tiles of T=128). 256 threads = 4 waves (2x2).
// Wave tile 64x64 via 4x4 blocks of v_mfma_f32_16x16x32_bf16.

#define TILE 128
#define IGRP 16
#define BS_STRIDE 136   // shorts per B-stage row (128 + 8 pad)
#define KRC_STRIDE 264  // shorts per shifted-K row
#define EP_STRIDE 132   // floats per epilogue row (128 + 4 pad)
#define SMEM_BYTES 39040

typedef short bf16x8 __attribute__((ext_vector_type(8)));
typedef float f32x4 __attribute__((ext_vector_type(4)));

__device__ __forceinline__ unsigned short f2bf(float f) {
    unsigned int u = __float_as_uint(f);
    u = (u + 0x7fffu + ((u >> 16) & 1u)) >> 16;  // RNE
    return (unsigned short)u;
}

__global__ void cvt_u_bf16(const float* __restrict__ u, unsigned short* __restrict__ ubf, int n4) {
    int idx = blockIdx.x * 256 + threadIdx.x;
    if (idx >= n4) return;
    float4 v = ((const float4*)u)[idx];
    ushort4 o;
    o.x = f2bf(v.x); o.y = f2bf(v.y); o.z = f2bf(v.z); o.w = f2bf(v.w);
    ((ushort4*)ubf)[idx] = o;
}

// KR[h][x] = bf16(K[h][L-1-x])  (reversed kernel rows)
__global__ void build_KR(const float* __restrict__ K, unsigned short* __restrict__ KR, int L) {
    int x = blockIdx.x * 256 + threadIdx.x;
    long h = blockIdx.y;
    if (x >= L) return;
    KR[h * L + x] = f2bf(K[h * L + (L - 1 - x)]);
}

__global__ __launch_bounds__(256, 2) void conv_main(
    const float* __restrict__ u, const float* __restrict__ Kc,
    const float* __restrict__ Dp, const unsigned short* __restrict__ ubf,
    const unsigned short* __restrict__ KR, float* __restrict__ outf,
    int H, int L, int G, int use_ws, int cplx, long out_floats)
{
    __shared__ __align__(16) char smem[SMEM_BYTES];
    unsigned short* Bs  = (unsigned short*)smem;           // 128*136 shorts = 34816 B
    unsigned short* Krc = (unsigned short*)(smem + 34816); // 8*264 shorts = 4224 B
    float*          Ep  = (float*)smem;                    // epilogue reuse: 64*132 f32

    const int tid  = threadIdx.x;
    const int lane = tid & 63;
    const int wv   = tid >> 6;
    const int wm   = wv >> 1;   // wave row (M half)
    const int wn   = wv & 1;    // wave col (N half)
    const int m    = lane & 15;
    const int quad = lane >> 4;

    const int bx = blockIdx.x;
    const int h  = bx % H;
    const int g  = (G - 1) - (bx / H);  // big groups dispatched first
    const int i0 = g * IGRP;
    const int dmax = i0 + IGRP - 1;

    f32x4 acc[4][4];
    {
        f32x4 z = {0.f, 0.f, 0.f, 0.f};
        #pragma unroll
        for (int a = 0; a < 4; ++a)
            #pragma unroll
            for (int b = 0; b < 4; ++b) acc[a][b] = z;
    }

    // B-staging mapping: thread -> (column, 64-element half-row)
    const int sc  = tid >> 1;        // column 0..127; col c -> i_local=c>>3, b=c&7
    const int sqo = (tid & 1) * 64;  // q offset
    const int sb  = sc & 7;
    const int sil = sc >> 3;
    const long urow = ((long)sb * H + h) * L;

    for (int d = 0; d <= dmax; ++d) {
        // ---- stage B tile: Bs[c][q] = ubf[b,h,(i0+il-d)*T + q] or 0 ----
        {
            int j = i0 + sil - d;
            uint4* dst = (uint4*)(Bs + sc * BS_STRIDE + sqo);
            if (j >= 0) {
                if (use_ws) {
                    const uint4* src = (const uint4*)(ubf + urow + (long)j * TILE + sqo);
                    #pragma unroll
                    for (int k = 0; k < 8; ++k) dst[k] = src[k];
                } else {
                    const float4* src = (const float4*)(u + urow + (long)j * TILE + sqo);
                    #pragma unroll
                    for (int k = 0; k < 16; ++k) {
                        float4 v = src[k];
                        ushort4 o;
                        o.x = f2bf(v.x); o.y = f2bf(v.y); o.z = f2bf(v.z); o.w = f2bf(v.w);
                        ((ushort4*)dst)[k] = o;
                    }
                }
            } else {
                uint4 z = {0u, 0u, 0u, 0u};
                #pragma unroll
                for (int k = 0; k < 8; ++k) dst[k] = z;
            }
        }
        // ---- stage reversed K, 8 shift copies: Krc[r][t'] = Krev[t'-r] ----
        // Krev[t] = K[h, d*T + 127 - t], zero outside [0,256) or K-index<0
        {
            const int xbase = L - TILE - d * TILE;  // KR index base
            for (int wi = tid; wi < 1056; wi += 256) {
                int r   = wi / 132;
                int dwp = wi - r * 132;
                int tp  = dwp * 2;
                int ta  = tp - r;
                int tb  = ta + 1;
                unsigned int s0 = 0, s1 = 0;
                if (use_ws) {
                    const unsigned short* krow = KR + (long)h * L + xbase;
                    if (ta >= 0 && ta < 256 && (xbase + ta) < L) s0 = krow[ta];
                    if (tb >= 0 && tb < 256 && (xbase + tb) < L) s1 = krow[tb];
                } else {
                    const float* krow = Kc + (long)h * L;
                    int ka = d * TILE + 127 - ta;
                    if (ta >= 0 && ta < 256 && ka >= 0) s0 = f2bf(krow[ka]);
                    if (tb >= 0 && tb < 256 && (ka - 1) >= 0) s1 = f2bf(krow[ka - 1]);
                }
                *(unsigned int*)(Krc + r * KRC_STRIDE + tp) = s0 | (s1 << 16);
            }
        }
        __syncthreads();

        // ---- compute: 4 kc chunks of K=32 ----
        const int dlim = d - i0;  // i_local alive iff i_local >= dlim
        #pragma unroll
        for (int kc = 0; kc < 4; ++kc) {
            bf16x8 af[4];
            #pragma unroll
            for (int rb = 0; rb < 4; ++rb) {
                int R  = wm * 64 + rb * 16;
                int t0 = 127 - R - m + kc * 32 + quad * 8;  // A[m][k]: m=lane&15, k=quad*8+j
                int r  = (m + 1) & 7;                        // shift copy making t0+r 8-aligned
                af[rb] = *(const bf16x8*)(Krc + r * KRC_STRIDE + (t0 + r));
            }
            #pragma unroll
            for (int nb = 0; nb < 4; ++nb) {
                int nbg = wn * 4 + nb;
                if (2 * nbg + 1 >= dlim) {  // skip fully-dead column blocks
                    int cg = wn * 64 + nb * 16 + m;  // B[k][n]: n=lane&15
                    bf16x8 bfr = *(const bf16x8*)(Bs + cg * BS_STRIDE + kc * 32 + quad * 8);
                    #pragma unroll
                    for (int rb = 0; rb < 4; ++rb)
                        acc[rb][nb] = __builtin_amdgcn_mfma_f32_16x16x32_bf16(af[rb], bfr, acc[rb][nb], 0, 0, 0);
                }
            }
        }
        __syncthreads();
    }

    // ---- epilogue: LDS transpose (2 passes of 64 cols), skip-add, store ----
    const float Dh = Dp[h];
    const int ec = tid >> 2;
    const int ps = (tid & 3) * 32;
    #pragma unroll
    for (int pass = 0; pass < 2; ++pass) {
        if (wn == pass) {
            #pragma unroll
            for (int rb = 0; rb < 4; ++rb) {
                int p = wm * 64 + rb * 16 + quad * 4;  // C/D: row = quad*4 + reg
                #pragma unroll
                for (int nb = 0; nb < 4; ++nb) {
                    int cloc = nb * 16 + m;            // C/D: col = lane&15
                    *(f32x4*)(Ep + cloc * EP_STRIDE + p) = acc[rb][nb];
                }
            }
        }
        __syncthreads();
        {
            int cg = pass * 64 + ec;
            int b  = cg & 7;
            int i  = i0 + (cg >> 3);
            long base = ((long)b * H + h) * L + (long)i * TILE + ps;
            const float* ep = Ep + ec * EP_STRIDE + ps;
            const float* us = u + base;
            if (cplx) {
                if (2 * (base + 32) <= out_floats) {
                    float4* o = (float4*)(outf + 2 * base);
                    #pragma unroll
                    for (int k4 = 0; k4 < 8; ++k4) {
                        float4 uv = ((const float4*)us)[k4];
                        float4 ev = *(const float4*)(ep + k4 * 4);
                        float4 o1, o2;
                        o1.x = ev.x + Dh * uv.x; o1.y = 0.f;
                        o1.z = ev.y + Dh * uv.y; o1.w = 0.f;
                        o2.x = ev.z + Dh * uv.z; o2.y = 0.f;
                        o2.z = ev.w + Dh * uv.w; o2.w = 0.f;
                        o[k4 * 2]     = o1;
                        o[k4 * 2 + 1] = o2;
                    }
                }
            } else {
                if (base + 32 <= out_floats) {
                    float4* o = (float4*)(outf + base);
                    #pragma unroll
                    for (int k4 = 0; k4 < 8; ++k4) {
                        float4 uv = ((const float4*)us)[k4];
                        float4 ev = *(const float4*)(ep + k4 * 4);
                        float4 ov;
                        ov.x = ev.x + Dh * uv.x;
                        ov.y = ev.y + Dh * uv.y;
                        ov.z = ev.z + Dh * uv.z;
                        ov.w = ev.w + Dh * uv.w;
                        o[k4] = ov;
                    }
                }
            }
        }
        __syncthreads();
    }
}

extern "C" void kernel_launch(void* const* d_in, const int* in_sizes, int n_in,
                              void* d_out, int out_size, void* d_ws, size_t ws_size,
                              hipStream_t stream) {
    const float* u  = (const float*)d_in[0];
    const float* Kc = (const float*)d_in[1];
    const float* Dp = (const float*)d_in[2];
    const int H = in_sizes[2];
    const int L = in_sizes[1] / H;          // 8192
    const int G = L / (TILE * IGRP);        // 4 groups of 16 tiles
    const size_t ubytes = (size_t)in_sizes[0] * 2;
    const size_t kbytes = (size_t)in_sizes[1] * 2;
    const int use_ws = (ws_size >= ubytes + kbytes) ? 1 : 0;
    const int cplx = (out_size >= 2 * in_sizes[0]) ? 1 : 0;
    unsigned short* ubf = (unsigned short*)d_ws;
    unsigned short* KR  = (unsigned short*)((char*)d_ws + ubytes);

    if (use_ws) {
        int n4 = in_sizes[0] / 4;
        cvt_u_bf16<<<(n4 + 255) / 256, 256, 0, stream>>>(u, ubf, n4);
        dim3 gk((L + 255) / 256, H);
        build_KR<<<gk, 256, 0, stream>>>(Kc, KR, L);
    }
    conv_main<<<H * G, 256, 0, stream>>>(u, Kc, Dp, ubf, KR, (float*)d_out,
                                         H, L, G, use_ws, cplx, (long)out_size);
}

// Round 3
// 307.398 us; speedup vs baseline: 1.2757x; 1.2757x over previous
//
#include <hip/hip_runtime.h>

// Causal Toeplitz-conv GEMM with sliding-window LDS circular buffer.
// y[b,h,n] = sum_{m<=n} u[b,h,m]*K[h,n-m] + D[h]*u[b,h,n]; out complex64 (re,0).
// Block = (h, group of IGRP=16 tiles of T=128), 256 thr = 4 waves (2x2), wave 64x64
// via 4x4 blocks of v_mfma_f32_16x16x32_bf16. Per iter: stage ONE new u-tile (2KB)
// + K-window into double-buffered 8-shift-copy region; ONE barrier per iter.

#define TILE 128
#define IGRP 16
#define SLOTS 17
#define ZSLOT 17
#define NSLOT 18
#define BROW 136                       // shorts per (slot,b) row (128 + 8 pad)
#define SLOT_STRIDE (8 * BROW)         // 1088 shorts per slot
#define KRC_STRIDE 264                 // shorts per shifted-K row
#define KRC_BUF (8 * KRC_STRIDE)       // 2112 shorts per K buffer
#define BS_SHORTS (NSLOT * SLOT_STRIDE)        // 19584
#define SMEM_BYTES ((BS_SHORTS + 2 * KRC_BUF) * 2)  // 47616
#define EP_STRIDE 132

typedef short bf16x8 __attribute__((ext_vector_type(8)));
typedef float f32x4 __attribute__((ext_vector_type(4)));

__device__ __forceinline__ unsigned short f2bf(float f) {
    unsigned int u = __float_as_uint(f);
    u = (u + 0x7fffu + ((u >> 16) & 1u)) >> 16;  // RNE
    return (unsigned short)u;
}

__global__ void cvt_u_bf16(const float* __restrict__ u, unsigned short* __restrict__ ubf, int n4) {
    int idx = blockIdx.x * 256 + threadIdx.x;
    if (idx >= n4) return;
    float4 v = ((const float4*)u)[idx];
    ushort4 o;
    o.x = f2bf(v.x); o.y = f2bf(v.y); o.z = f2bf(v.z); o.w = f2bf(v.w);
    ((ushort4*)ubf)[idx] = o;
}

__global__ void build_KR(const float* __restrict__ K, unsigned short* __restrict__ KR, int L) {
    int x = blockIdx.x * 256 + threadIdx.x;
    long h = blockIdx.y;
    if (x >= L) return;
    KR[h * L + x] = f2bf(K[h * L + (L - 1 - x)]);
}

__global__ __launch_bounds__(256, 2) void conv_main(
    const float* __restrict__ u, const float* __restrict__ Kc,
    const float* __restrict__ Dp, const unsigned short* __restrict__ ubf,
    const unsigned short* __restrict__ KR, float* __restrict__ outf,
    int H, int L, int G, int use_ws, int cplx, long out_floats)
{
    __shared__ __align__(16) char smem[SMEM_BYTES];
    unsigned short* Bs  = (unsigned short*)smem;
    unsigned short* Krc = Bs + BS_SHORTS;
    float*          Ep  = (float*)smem;

    const int tid  = threadIdx.x;
    const int lane = tid & 63;
    const int wv   = tid >> 6;
    const int wm   = wv >> 1;
    const int wn   = wv & 1;
    const int m    = lane & 15;
    const int quad = lane >> 4;

    const int bx = blockIdx.x;
    const int h  = bx % H;
    const int g  = (G - 1) - (bx / H);
    const int i0 = g * IGRP;
    const int dmax = i0 + IGRP - 1;

    // per-lane fragment-address constants
    const int rA = (m + 1) & 7;
    const int cA = 127 - wm * 64 - m + quad * 8 + rA * KRC_STRIDE + rA;  // shorts
    const int cB = (m & 7) * BROW + quad * 8;                            // shorts

    // K-staging thread constants: wi = tid + 256p covers 1056 u32 writes
    int ldsK[5], taK[5];
    bool vK[5];
    #pragma unroll
    for (int p = 0; p < 5; ++p) {
        int wi = tid + p * 256;
        vK[p] = wi < 1056;
        int rp = vK[p] ? (wi / 132) : 0;
        int dwp = wi - rp * 132;
        int tp = dwp * 2;
        ldsK[p] = rp * KRC_STRIDE + tp;
        taK[p] = vK[p] ? (tp - rp) : -1000;
    }
    const unsigned short* KRrow = KR + (long)h * L;
    const float*          Kfrow = Kc + (long)h * L;

    // B-staging thread mapping: one (b, 4q) chunk per thread
    const int bb = tid >> 5;
    const int q8 = (tid & 31) * 4;
    const long ubase = ((long)bb * H + h) * L;

    f32x4 acc[4][4];
    {
        f32x4 z = {0.f, 0.f, 0.f, 0.f};
        #pragma unroll
        for (int a = 0; a < 4; ++a)
            #pragma unroll
            for (int b = 0; b < 4; ++b) acc[a][b] = z;
    }

    // per-nb column tile trackers (j decrements each iter; slot wraps mod 17)
    int jc[4], sc4[4];
    #pragma unroll
    for (int nb = 0; nb < 4; ++nb) {
        int il = wn * 8 + nb * 2 + (m >> 3);
        jc[nb] = i0 + il;
        sc4[nb] = jc[nb] % SLOTS;
    }
    int slotw = (i0 >= 1) ? ((i0 - 1) % SLOTS) : (SLOTS - 1);  // slot for tile i0-1-d

    // ---- prologue: zero-slot, 16 window tiles, Krc[0] ----
    {
        unsigned int* zp = (unsigned int*)(Bs + ZSLOT * SLOT_STRIDE);
        for (int t = tid; t < SLOT_STRIDE / 2; t += 256) zp[t] = 0;
    }
    #pragma unroll
    for (int batch = 0; batch < 2; ++batch) {
        uint2 a8[8];
        #pragma unroll
        for (int q = 0; q < 8; ++q) {
            int j = i0 + batch * 8 + q;
            if (use_ws) {
                a8[q] = *(const uint2*)(ubf + ubase + (long)j * TILE + q8);
            } else {
                float4 v = *(const float4*)(u + ubase + (long)j * TILE + q8);
                a8[q].x = f2bf(v.x) | ((unsigned)f2bf(v.y) << 16);
                a8[q].y = f2bf(v.z) | ((unsigned)f2bf(v.w) << 16);
            }
        }
        #pragma unroll
        for (int q = 0; q < 8; ++q) {
            int j = i0 + batch * 8 + q;
            int sl = j % SLOTS;
            *(uint2*)(Bs + sl * SLOT_STRIDE + bb * BROW + q8) = a8[q];
        }
    }
    {
        const int xbn = L - TILE;  // dn = 0
        #pragma unroll
        for (int p = 0; p < 5; ++p) {
            if (vK[p]) {
                unsigned int s0 = 0, s1 = 0;
                int ta = taK[p];
                if (use_ws) {
                    int xa = xbn + ta;
                    if (ta >= 0 && ta < 256 && xa < L) s0 = KRrow[xa];
                    if (ta + 1 >= 0 && ta + 1 < 256 && (xa + 1) < L) s1 = KRrow[xa + 1];
                } else {
                    int ka = 127 - ta;
                    if (ta >= 0 && ta < 256 && ka >= 0) s0 = f2bf(Kfrow[ka]);
                    if (ta + 1 >= 0 && ta + 1 < 256 && (ka - 1) >= 0) s1 = f2bf(Kfrow[ka - 1]);
                }
                *(unsigned int*)(Krc + ldsK[p]) = s0 | (s1 << 16);
            }
        }
    }
    __syncthreads();

    // ---- main loop: one barrier per iter ----
    for (int d = 0; d <= dmax; ++d) {
        const int dn = d + 1;
        const int jn = i0 - dn;
        const bool doK = (dn <= dmax);

        // issue loads for iter d+1 (hidden behind compute)
        uint2 bv = {0u, 0u};
        if (jn >= 0) {
            if (use_ws) {
                bv = *(const uint2*)(ubf + ubase + (long)jn * TILE + q8);
            } else {
                float4 v = *(const float4*)(u + ubase + (long)jn * TILE + q8);
                bv.x = f2bf(v.x) | ((unsigned)f2bf(v.y) << 16);
                bv.y = f2bf(v.z) | ((unsigned)f2bf(v.w) << 16);
            }
        }
        unsigned int kv[5] = {0u, 0u, 0u, 0u, 0u};
        if (doK) {
            const int xbn = L - TILE - dn * TILE;
            #pragma unroll
            for (int p = 0; p < 5; ++p) {
                unsigned int s0 = 0, s1 = 0;
                int ta = taK[p];
                if (vK[p]) {
                    if (use_ws) {
                        int xa = xbn + ta;
                        if (ta >= 0 && ta < 256 && xa < L) s0 = KRrow[xa];
                        if (ta + 1 >= 0 && ta + 1 < 256 && (xa + 1) < L) s1 = KRrow[xa + 1];
                    } else {
                        int ka = dn * TILE + 127 - ta;
                        if (ta >= 0 && ta < 256 && ka >= 0) s0 = f2bf(Kfrow[ka]);
                        if (ta + 1 >= 0 && ta + 1 < 256 && (ka - 1) >= 0) s1 = f2bf(Kfrow[ka - 1]);
                    }
                }
                kv[p] = s0 | (s1 << 16);
            }
        }

        // compute iter d
        const int dlim = d - i0;
        const unsigned short* Ab = Krc + (d & 1) * KRC_BUF + cA;
        const unsigned short* Bp[4];
        #pragma unroll
        for (int nb = 0; nb < 4; ++nb)
            Bp[nb] = Bs + ((jc[nb] >= 0 ? sc4[nb] : ZSLOT) * SLOT_STRIDE) + cB;

        bf16x8 af0, af1, af2, af3;
        #pragma unroll
        for (int kc = 0; kc < 4; ++kc) {
            if (kc == 0) {
                af0 = *(const bf16x8*)(Ab);
                af1 = *(const bf16x8*)(Ab - 16);
                af2 = *(const bf16x8*)(Ab - 32);
                af3 = *(const bf16x8*)(Ab - 48);
            } else {
                af2 = af0; af3 = af1;
                af0 = *(const bf16x8*)(Ab + kc * 32);
                af1 = *(const bf16x8*)(Ab + kc * 32 - 16);
            }
            #pragma unroll
            for (int nb = 0; nb < 4; ++nb) {
                const int nbg = wn * 4 + nb;
                if (2 * nbg + 1 >= dlim) {  // skip fully-dead column blocks
                    bf16x8 bfr = *(const bf16x8*)(Bp[nb] + kc * 32);
                    acc[0][nb] = __builtin_amdgcn_mfma_f32_16x16x32_bf16(af0, bfr, acc[0][nb], 0, 0, 0);
                    acc[1][nb] = __builtin_amdgcn_mfma_f32_16x16x32_bf16(af1, bfr, acc[1][nb], 0, 0, 0);
                    acc[2][nb] = __builtin_amdgcn_mfma_f32_16x16x32_bf16(af2, bfr, acc[2][nb], 0, 0, 0);
                    acc[3][nb] = __builtin_amdgcn_mfma_f32_16x16x32_bf16(af3, bfr, acc[3][nb], 0, 0, 0);
                }
            }
        }

        // commit staged data for iter d+1 (targets not read this iter)
        if (doK) {
            unsigned short* Kw = Krc + (dn & 1) * KRC_BUF;
            #pragma unroll
            for (int p = 0; p < 5; ++p)
                if (vK[p]) *(unsigned int*)(Kw + ldsK[p]) = kv[p];
        }
        if (jn >= 0)
            *(uint2*)(Bs + slotw * SLOT_STRIDE + bb * BROW + q8) = bv;

        slotw = slotw ? slotw - 1 : SLOTS - 1;
        #pragma unroll
        for (int nb = 0; nb < 4; ++nb) {
            jc[nb]--;
            sc4[nb] = sc4[nb] ? sc4[nb] - 1 : SLOTS - 1;
        }
        __syncthreads();
    }

    // ---- epilogue: LDS transpose (2 passes), skip-add, store ----
    const float Dh = Dp[h];
    const int ec = tid >> 2;
    const int ps = (tid & 3) * 32;
    #pragma unroll
    for (int pass = 0; pass < 2; ++pass) {
        if (wn == pass) {
            #pragma unroll
            for (int rb = 0; rb < 4; ++rb) {
                int p = wm * 64 + rb * 16 + quad * 4;  // C/D: row = quad*4 + reg
                #pragma unroll
                for (int nb = 0; nb < 4; ++nb) {
                    int cloc = nb * 16 + m;            // C/D: col = lane&15
                    *(f32x4*)(Ep + cloc * EP_STRIDE + p) = acc[rb][nb];
                }
            }
        }
        __syncthreads();
        {
            int cg = pass * 64 + ec;
            int b  = cg & 7;
            int i  = i0 + (cg >> 3);
            long base = ((long)b * H + h) * L + (long)i * TILE + ps;
            const float* ep = Ep + ec * EP_STRIDE + ps;
            const float* us = u + base;
            if (cplx) {
                if (2 * (base + 32) <= out_floats) {
                    float4* o = (float4*)(outf + 2 * base);
                    #pragma unroll
                    for (int k4 = 0; k4 < 8; ++k4) {
                        float4 uv = ((const float4*)us)[k4];
                        float4 ev = *(const float4*)(ep + k4 * 4);
                        float4 o1, o2;
                        o1.x = ev.x + Dh * uv.x; o1.y = 0.f;
                        o1.z = ev.y + Dh * uv.y; o1.w = 0.f;
                        o2.x = ev.z + Dh * uv.z; o2.y = 0.f;
                        o2.z = ev.w + Dh * uv.w; o2.w = 0.f;
                        o[k4 * 2]     = o1;
                        o[k4 * 2 + 1] = o2;
                    }
                }
            } else {
                if (base + 32 <= out_floats) {
                    float4* o = (float4*)(outf + base);
                    #pragma unroll
                    for (int k4 = 0; k4 < 8; ++k4) {
                        float4 uv = ((const float4*)us)[k4];
                        float4 ev = *(const float4*)(ep + k4 * 4);
                        float4 ov;
                        ov.x = ev.x + Dh * uv.x;
                        ov.y = ev.y + Dh * uv.y;
                        ov.z = ev.z + Dh * uv.z;
                        ov.w = ev.w + Dh * uv.w;
                        o[k4] = ov;
                    }
                }
            }
        }
        __syncthreads();
    }
}

extern "C" void kernel_launch(void* const* d_in, const int* in_sizes, int n_in,
                              void* d_out, int out_size, void* d_ws, size_t ws_size,
                              hipStream_t stream) {
    const float* u  = (const float*)d_in[0];
    const float* Kc = (const float*)d_in[1];
    const float* Dp = (const float*)d_in[2];
    const int H = in_sizes[2];
    const int L = in_sizes[1] / H;          // 8192
    const int G = L / (TILE * IGRP);        // 4
    const size_t ubytes = (size_t)in_sizes[0] * 2;
    const size_t kbytes = (size_t)in_sizes[1] * 2;
    const int use_ws = (ws_size >= ubytes + kbytes) ? 1 : 0;
    const int cplx = (out_size >= 2 * in_sizes[0]) ? 1 : 0;
    unsigned short* ubf = (unsigned short*)d_ws;
    unsigned short* KR  = (unsigned short*)((char*)d_ws + ubytes);

    if (use_ws) {
        int n4 = in_sizes[0] / 4;
        cvt_u_bf16<<<(n4 + 255) / 256, 256, 0, stream>>>(u, ubf, n4);
        dim3 gk((L + 255) / 256, H);
        build_KR<<<gk, 256, 0, stream>>>(Kc, KR, L);
    }
    conv_main<<<H * G, 256, 0, stream>>>(u, Kc, Dp, ubf, KR, (float*)d_out,
                                         H, L, G, use_ws, cplx, (long)out_size);
}